// Round 3
// baseline (2185.365 us; speedup 1.0000x reference)
//
#include <hip/hip_runtime.h>
#include <cstdint>
#include <cstddef>

#define SEQ 512
#define BATCH 256
#define SD 1024
#define OD 256
#define NG 16          // groups (batch tiles)
#define GB 16          // batches per group
#define NW 16          // workgroups per group

// 8 bf16 values packed as shorts (4 VGPRs) -- guide-verified MFMA frag type
typedef short  bf8   __attribute__((ext_vector_type(8)));
typedef float  f32x4 __attribute__((ext_vector_type(4)));

union BF16x8 { unsigned long long q[2]; bf8 v; };

#define TAGM 0x0001000100010001ULL   // LSB of each 16-bit lane = phase tag

__device__ __forceinline__ unsigned short f2bf(float f) {
    unsigned u = __float_as_uint(f);
    u += 0x7FFFu + ((u >> 16) & 1u);      // round-to-nearest-even
    return (unsigned short)(u >> 16);
}

__device__ __forceinline__ float fast_tanh(float v) {
    float e = __expf(2.0f * v);
    return 1.0f - 2.0f / (e + 1.0f);
}

// tag for t_i: alternates on each rewrite of a buffer word; ^1 so that the
// first write to each buffer (i=0,1) has tag=1, distinct from 0xAA poison
// (whose 16-bit LSBs are 0).
__device__ __forceinline__ unsigned tag_of(int i) {
    return (((unsigned)i >> 1) & 1u) ^ 1u;
}

// Barrier-free persistent kernel: 256 wgs = 16 groups x 16 wgs. Group owns 16
// batches; wg owns 64 state-cols of w_r (reg-resident bf16 frags) + 16 out-
// cols of w_o. The t = tanh(h) tile is exchanged through a DOUBLE-buffered
// sc1 (device-coherence-point) region where each 64-bit word carries its own
// phase parity in the 4 bf16 LSBs (seqlock). Consumers poll their exact MFMA
// A-fragment words until parity matches -- accepted words ARE the data: one
// coherence round trip per step instead of 4 (store/add/flag/load).
// 2-buffer safety: publishing t_{i+2} requires having consumed ALL of t_{i+1},
// which requires every wg (full-K coverage) to have finished reading t_i.
__global__ void __launch_bounds__(256, 1)
rnn_persistent(const float* __restrict__ x,
               const float* __restrict__ h_init,
               const float* __restrict__ w_r,
               const float* __restrict__ b_r,
               const float* __restrict__ w_o,
               const float* __restrict__ b_o,
               float* __restrict__ out,
               unsigned char* __restrict__ ws)
{
    const int wg   = blockIdx.x;
    const int g    = wg & 15;      // group
    const int wi   = wg >> 4;      // 0..15 within group
    const int tid  = threadIdx.x;
    const int lane = tid & 63;
    const int wid  = tid >> 6;     // wave 0..3
    const int l15  = lane & 15;
    const int lq   = lane >> 4;    // k-quad 0..3

    unsigned short* tbase = (unsigned short*)ws;  // 2 x [256][1024] bf16

    const int batch0 = g * GB;     // group's batch rows
    const int s0 = wi * 64;        // wg's state cols
    const int o0 = wi * 16;        // wg's output cols
    const int k0 = wid * 256;      // wave's K slice

    __shared__ float red1[4][4][4][68];  // [wave][coltile][reg][lane] (+4 pad)
    __shared__ float red2[4][4][68];     // [wave][reg][lane]

    // ---- preload w_r slice as B fragments in registers (128 VGPRs) ----
    bf8 B1[4][8];
#pragma unroll
    for (int ct = 0; ct < 4; ++ct) {
#pragma unroll
        for (int kk = 0; kk < 8; ++kk) {
            const float* p = w_r + (size_t)(s0 + ct * 16 + l15) * SD + (k0 + kk * 32 + lq * 8);
            bf8 f;
#pragma unroll
            for (int j = 0; j < 8; ++j) f[j] = (short)f2bf(p[j]);
            B1[ct][kk] = f;
        }
    }
    // ---- w_o slice: 16 rows -> full N=16 tile ----
    bf8 B2[8];
#pragma unroll
    for (int kk = 0; kk < 8; ++kk) {
        const float* p = w_o + (size_t)(o0 + l15) * SD + (k0 + kk * 32 + lq * 8);
        bf8 f;
#pragma unroll
        for (int j = 0; j < 8; ++j) f[j] = (short)f2bf(p[j]);
        B2[kk] = f;
    }

    // ---- per-thread h ownership: 4 consecutive states of one batch row ----
    const int hr = tid >> 4;            // batch-local row 0..15
    const int hc = (tid & 15) * 4;      // state-local col base (one aligned qword)
    float4 br4  = *(const float4*)(b_r + s0 + hc);
    float4 hreg = *(const float4*)(h_init + (size_t)(batch0 + hr) * SD + s0 + hc);

    const int ct1 = hc >> 4;
    const int rg1 = hr & 3;
    const int ln1 = (hr >> 2) * 16 + (hc & 15);

    const int er  = tid >> 4;           // err element (row, col)
    const int ec  = tid & 15;
    const int rg2 = er & 3;
    const int ln2 = (er >> 2) * 16 + ec;
    const float bo = b_o[o0 + ec];

    const size_t t_qoff = ((size_t)(batch0 + hr) * SD + s0 + hc) >> 2;  // qword index

    // qword base of this wave's A-fragment slice (16 rows x wave K-slice)
    const size_t a_qoff = ((size_t)(batch0 + l15) * SD + k0 + lq * 8) >> 2;

    bf8 A[8];  // A fragments of current t tile (reused by gemm1 AND gemm2)

    // ---- publish 4 tanh values as one tagged qword (LSB of each bf16 = tag) ----
    auto publish = [&](int buf, unsigned tag) {
        unsigned long long v =
              (unsigned long long)((f2bf(fast_tanh(hreg.x)) & 0xFFFEu) | tag)
            | ((unsigned long long)((f2bf(fast_tanh(hreg.y)) & 0xFFFEu) | tag) << 16)
            | ((unsigned long long)((f2bf(fast_tanh(hreg.z)) & 0xFFFEu) | tag) << 32)
            | ((unsigned long long)((f2bf(fast_tanh(hreg.w)) & 0xFFFEu) | tag) << 48);
        unsigned long long* p = (unsigned long long*)tbase + (size_t)buf * (BATCH * SD / 4) + t_qoff;
        __hip_atomic_store(p, v, __ATOMIC_RELAXED, __HIP_MEMORY_SCOPE_AGENT);
    };

    // ---- poll this wave's 16 A-fragment qwords until parity == tag ----
    auto poll_A = [&](int buf, unsigned tag) {
        const unsigned long long* ap =
            (const unsigned long long*)tbase + (size_t)buf * (BATCH * SD / 4) + a_qoff;
        const unsigned long long exp64 = tag ? TAGM : 0ULL;
        unsigned long long q[16];
        bool ok;
        do {
#pragma unroll
            for (int kk = 0; kk < 8; ++kk) {
                q[2 * kk]     = __hip_atomic_load(ap + kk * 8,     __ATOMIC_RELAXED, __HIP_MEMORY_SCOPE_AGENT);
                q[2 * kk + 1] = __hip_atomic_load(ap + kk * 8 + 1, __ATOMIC_RELAXED, __HIP_MEMORY_SCOPE_AGENT);
            }
            ok = true;
#pragma unroll
            for (int k = 0; k < 16; ++k) ok &= (((q[k] ^ exp64) & TAGM) == 0ULL);
        } while (!__all(ok));
#pragma unroll
        for (int kk = 0; kk < 8; ++kk) {
            BF16x8 u;
            u.q[0] = q[2 * kk];
            u.q[1] = q[2 * kk + 1];
            A[kk] = u.v;
        }
    };

    auto gemm2 = [&](int tstep, float xv) {
        f32x4 c = {0.f, 0.f, 0.f, 0.f};
#pragma unroll
        for (int kk = 0; kk < 8; ++kk)
            c = __builtin_amdgcn_mfma_f32_16x16x32_bf16(A[kk], B2[kk], c, 0, 0, 0);
#pragma unroll
        for (int q = 0; q < 4; ++q) red2[wid][q][lane] = c[q];
        __syncthreads();
        float sum = red2[0][rg2][ln2] + red2[1][rg2][ln2]
                  + red2[2][rg2][ln2] + red2[3][rg2][ln2];
        size_t oidx = (size_t)tstep * (BATCH * OD) + (size_t)(batch0 + er) * OD + o0 + ec;
        out[oidx] = sum + bo - xv;
    };

    // ---- t0 = tanh(h_init) into buffer 0, tag 1 ----
    publish(0, 1u);

    for (int i = 0; i < SEQ; ++i) {
        // prefetch x for err_{i-1} (consumed ~1000 cycles from now)
        float xv = 0.f;
        size_t oidx_prev = 0;
        if (i >= 1) {
            oidx_prev = (size_t)(i - 1) * (BATCH * OD) + (size_t)(batch0 + er) * OD + o0 + ec;
            xv = x[oidx_prev];
        }

        // ---- data-driven wait: A frags of t_i (per-wave dependency) ----
        poll_A(i & 1, tag_of(i));

        // ---- recurrent GEMM: C[16x64] per wave over its K slice ----
        f32x4 acc0 = {0.f,0.f,0.f,0.f}, acc1 = {0.f,0.f,0.f,0.f};
        f32x4 acc2 = {0.f,0.f,0.f,0.f}, acc3 = {0.f,0.f,0.f,0.f};
#pragma unroll
        for (int kk = 0; kk < 8; ++kk) {
            acc0 = __builtin_amdgcn_mfma_f32_16x16x32_bf16(A[kk], B1[0][kk], acc0, 0, 0, 0);
            acc1 = __builtin_amdgcn_mfma_f32_16x16x32_bf16(A[kk], B1[1][kk], acc1, 0, 0, 0);
            acc2 = __builtin_amdgcn_mfma_f32_16x16x32_bf16(A[kk], B1[2][kk], acc2, 0, 0, 0);
            acc3 = __builtin_amdgcn_mfma_f32_16x16x32_bf16(A[kk], B1[3][kk], acc3, 0, 0, 0);
        }
#pragma unroll
        for (int q = 0; q < 4; ++q) {
            red1[wid][0][q][lane] = acc0[q];
            red1[wid][1][q][lane] = acc1[q];
            red1[wid][2][q][lane] = acc2[q];
            red1[wid][3][q][lane] = acc3[q];
        }
        __syncthreads();

        // ---- K-reduction across 4 waves + leaky h update + publish ASAP ----
        float4 p0 = *(const float4*)&red1[0][ct1][rg1][ln1];
        float4 p1 = *(const float4*)&red1[1][ct1][rg1][ln1];
        float4 p2 = *(const float4*)&red1[2][ct1][rg1][ln1];
        float4 p3 = *(const float4*)&red1[3][ct1][rg1][ln1];
        hreg.x = 0.9f * hreg.x + 0.1f * (p0.x + p1.x + p2.x + p3.x + br4.x);
        hreg.y = 0.9f * hreg.y + 0.1f * (p0.y + p1.y + p2.y + p3.y + br4.y);
        hreg.z = 0.9f * hreg.z + 0.1f * (p0.z + p1.z + p2.z + p3.z + br4.z);
        hreg.w = 0.9f * hreg.w + 0.1f * (p0.w + p1.w + p2.w + p3.w + br4.w);
        publish((i + 1) & 1, tag_of(i + 1));

        // ---- off-critical-path: err_{i-1} reuses this step's A frags ----
        // (consumers need ~1 coherence round trip to detect our publish anyway)
        if (i >= 1) gemm2(i - 1, xv);

        __syncthreads();  // don't let fast waves touch red1 before slow waves read it
    }

    // ---- epilogue: err_{511} from t_512 ----
    {
        size_t oidx = (size_t)(SEQ - 1) * (BATCH * OD) + (size_t)(batch0 + er) * OD + o0 + ec;
        float xv = x[oidx];
        poll_A(SEQ & 1, tag_of(SEQ));
        gemm2(SEQ - 1, xv);
    }
}

extern "C" void kernel_launch(void* const* d_in, const int* in_sizes, int n_in,
                              void* d_out, int out_size, void* d_ws, size_t ws_size,
                              hipStream_t stream)
{
    const float* x      = (const float*)d_in[0];
    const float* h_init = (const float*)d_in[1];
    const float* w_r    = (const float*)d_in[2];
    const float* b_r    = (const float*)d_in[3];
    const float* w_o    = (const float*)d_in[4];
    const float* b_o    = (const float*)d_in[5];
    float* out = (float*)d_out;

    // ws layout: 2 x 512 KB double-buffered t tile (self-tagged; poison-safe,
    // no memset needed -- 0xAA has LSB=0, first-use tag=1)
    rnn_persistent<<<dim3(256), dim3(256), 0, stream>>>(
        x, h_init, w_r, b_r, w_o, b_o, out, (unsigned char*)d_ws);
}